// Round 2
// baseline (356.850 us; speedup 1.0000x reference)
//
#include <hip/hip_runtime.h>

#define N_IMG 2048
#define SRC   64
#define PADW  32
#define TH    128
#define TW    128

// LDS layout: [ 66-elem zero pad | 64x64 interleaved (fill,stroke) | 66-elem zero pad ]
// Front pad of 66 keeps base index >= 0 for clamped (x0,y0) >= (-1,-1) and is
// 16B-aligned (66*8=528) so the staging float4 writes stay aligned.
#define LPAD  66
#define LSZ   (LPAD + SRC * SRC + 66)   // 4228 float2 = 33824 B

__global__ __launch_bounds__(256) void affine_sample_kernel(
    const float* __restrict__ affine,
    const float* __restrict__ fill,
    const float* __restrict__ stroke,
    float* __restrict__ out)
{
    __shared__ float2 sFS[LSZ];

    const int n = blockIdx.x;
    const float* __restrict__ fptr = fill   + (size_t)n * SRC * SRC;
    const float* __restrict__ sptr = stroke + (size_t)n * SRC * SRC;

    // Zero the guard pads (their values are multiplied by 0-weights, but must
    // not be NaN garbage).
    if (threadIdx.x < LPAD) {
        sFS[threadIdx.x] = make_float2(0.f, 0.f);
        sFS[LPAD + SRC * SRC + threadIdx.x] = make_float2(0.f, 0.f);
    }

    // Stage both images interleaved: sFS[LPAD + i] = (fill[i], stroke[i]).
    // float4 global loads, paired ds writes.
    for (int i = threadIdx.x; i < SRC * SRC / 4; i += 256) {
        const float4 f = reinterpret_cast<const float4*>(fptr)[i];
        const float4 s = reinterpret_cast<const float4*>(sptr)[i];
        float2* dst = &sFS[LPAD + 4 * i];
        dst[0] = make_float2(f.x, s.x);
        dst[1] = make_float2(f.y, s.y);
        dst[2] = make_float2(f.z, s.z);
        dst[3] = make_float2(f.w, s.w);
    }

    // Theta (computed redundantly per thread; 6 cached scalar loads + a few
    // transcendentals — negligible).
    const float t0 = affine[n * 6 + 0];
    const float t1 = affine[n * 6 + 1];
    const float t2 = affine[n * 6 + 2];
    const float t3 = affine[n * 6 + 3];
    const float t4 = affine[n * 6 + 4];
    const float t5 = affine[n * 6 + 5];
    const float a00 = 2.0f / (1.0f + __expf(-t0));
    const float a11 = 2.0f / (1.0f + __expf(-t1));
    const float a01 = 2.0f * tanhf(t2);
    const float a10 = 2.0f * tanhf(t3);
    const float a02 = tanhf(t4);
    const float a12 = tanhf(t5);

    __syncthreads();

    float* __restrict__ outF = out + (size_t)n * TH * TW;
    float* __restrict__ outS = out + (size_t)N_IMG * TH * TW + (size_t)n * TH * TW;

    // Source-coordinate sampling position for output pixel (px, py):
    //   isx = a00*(px+0.5) + 64*(a01*Y + a02 - a00) + 31.5   (PAD folded in)
    //   isy = a10*(px+0.5) + 64*(a11*Y + a12 - a10) + 31.5
    for (int q = threadIdx.x; q < TH * TW / 4; q += 256) {
        const int py  = q >> 5;
        const int pxb = (q & 31) << 2;
        const float Y  = ((float)py + 0.5f) * (2.0f / TH) - 1.0f;
        const float Cx = 64.0f * (a01 * Y + a02 - a00) + 31.5f;
        const float Cy = 64.0f * (a11 * Y + a12 - a10) + 31.5f;

        float rf[4], rs[4];

        #pragma unroll
        for (int j = 0; j < 4; ++j) {
            const float fx  = (float)(pxb + j) + 0.5f;
            const float isx = fmaf(a00, fx, Cx);
            const float isy = fmaf(a10, fx, Cy);

            const float x0f = floorf(isx);
            const float y0f = floorf(isy);
            const float wx  = isx - x0f;
            const float wy  = isy - y0f;
            const int   x0  = (int)x0f;
            const int   y0  = (int)y0f;

            // Mask-folded 1D weights (branchless; corner valid iff its source
            // index is in [0, 64)).
            const float wxa = ((unsigned)x0       < (unsigned)SRC) ? (1.0f - wx) : 0.0f;
            const float wxb = ((unsigned)(x0 + 1) < (unsigned)SRC) ? wx          : 0.0f;
            const float wya = ((unsigned)y0       < (unsigned)SRC) ? (1.0f - wy) : 0.0f;
            const float wyb = ((unsigned)(y0 + 1) < (unsigned)SRC) ? wy          : 0.0f;

            // Clamp so all 4 reads stay inside the padded LDS array; invalid
            // corners carry zero weight (and pads are zeroed).
            const int xc = min(max(x0, -1), SRC - 1);
            const int yc = min(max(y0, -1), SRC - 1);
            const int base = LPAD + yc * SRC + xc;

            const float2 v00 = sFS[base];
            const float2 v10 = sFS[base + 1];
            const float2 v01 = sFS[base + SRC];
            const float2 v11 = sFS[base + SRC + 1];

            const float w00 = wxa * wya;
            const float w10 = wxb * wya;
            const float w01 = wxa * wyb;
            const float w11 = wxb * wyb;

            rf[j] = w00 * v00.x + w10 * v10.x + w01 * v01.x + w11 * v11.x;
            rs[j] = w00 * v00.y + w10 * v10.y + w01 * v01.y + w11 * v11.y;
        }

        reinterpret_cast<float4*>(outF)[q] = make_float4(rf[0], rf[1], rf[2], rf[3]);
        reinterpret_cast<float4*>(outS)[q] = make_float4(rs[0], rs[1], rs[2], rs[3]);
    }
}

extern "C" void kernel_launch(void* const* d_in, const int* in_sizes, int n_in,
                              void* d_out, int out_size, void* d_ws, size_t ws_size,
                              hipStream_t stream) {
    const float* affine = (const float*)d_in[0];  // (N, 6)
    const float* fill   = (const float*)d_in[1];  // (N, 64, 64)
    const float* stroke = (const float*)d_in[2];  // (N, 64, 64)
    // d_in[3] = targetsize, unused by the computation.
    float* out = (float*)d_out;                   // fill_out then stroke_out, each (N,128,128)

    affine_sample_kernel<<<dim3(N_IMG), dim3(256), 0, stream>>>(affine, fill, stroke, out);
}

// Round 3
// 330.316 us; speedup vs baseline: 1.0803x; 1.0803x over previous
//
#include <hip/hip_runtime.h>

#define N_IMG 2048
#define SRC   64
#define TH    128
#define TW    128
// Padded LDS image: source cols/rows -2..65 stored at 0..67 (2-wide zero ring).
// clamp(x0, -2, 64) then +2 => all four bilinear corners read in-bounds, and
// every invalid/pad corner reads a structural zero. No per-corner masks.
#define LW    68
#define LN    (LW * LW)   // 4624 floats = 18496 B per image

typedef float v2f __attribute__((ext_vector_type(2)));

__global__ __launch_bounds__(256) void affine_sample_kernel(
    const float* __restrict__ affine,
    const float* __restrict__ fill,
    const float* __restrict__ stroke,
    float* __restrict__ out)
{
    __shared__ float sF[LN];
    __shared__ float sS[LN];   // static offset from sF => shared vaddr, imm offsets

    const int n   = blockIdx.x;
    const int tid = threadIdx.x;

    // --- Zero the 2-wide border ring (disjoint from interior; one sync later).
    // rows 0,1,66,67 (full width): 2*68 = 136 index pairs
    for (int i = tid; i < 136; i += 256) {
        const int r = i / LW, c = i % LW;          // r in {0,1}
        sF[r * LW + c] = 0.f;  sF[(67 - r) * LW + c] = 0.f;
        sS[r * LW + c] = 0.f;  sS[(67 - r) * LW + c] = 0.f;
    }
    // cols 0,1,66,67 for rows 2..65: 64*2 = 128 index pairs
    for (int i = tid; i < 128; i += 256) {
        const int r = 2 + (i >> 1), c = i & 1;     // c in {0,1}
        sF[r * LW + c] = 0.f;  sF[r * LW + 67 - c] = 0.f;
        sS[r * LW + c] = 0.f;  sS[r * LW + 67 - c] = 0.f;
    }

    // --- Stage interior with float4 global loads (coalesced).
    const float* __restrict__ fptr = fill   + (size_t)n * SRC * SRC;
    const float* __restrict__ sptr = stroke + (size_t)n * SRC * SRC;
    for (int i = tid; i < SRC * SRC / 4; i += 256) {
        const float4 f = reinterpret_cast<const float4*>(fptr)[i];
        const float4 s = reinterpret_cast<const float4*>(sptr)[i];
        const int y  = i >> 4;            // 16 groups of 4 per 64-wide row
        const int x4 = (i & 15) << 2;
        const int d  = (y + 2) * LW + x4 + 2;
        sF[d] = f.x; sF[d + 1] = f.y; sF[d + 2] = f.z; sF[d + 3] = f.w;
        sS[d] = s.x; sS[d + 1] = s.y; sS[d + 2] = s.z; sS[d + 3] = s.w;
    }

    // --- Theta (redundant per thread; negligible).
    const float t0 = affine[n * 6 + 0];
    const float t1 = affine[n * 6 + 1];
    const float t2 = affine[n * 6 + 2];
    const float t3 = affine[n * 6 + 3];
    const float t4 = affine[n * 6 + 4];
    const float t5 = affine[n * 6 + 5];
    const float a00 = 2.0f / (1.0f + __expf(-t0));
    const float a11 = 2.0f / (1.0f + __expf(-t1));
    const float a01 = 2.0f * tanhf(t2);
    const float a10 = 2.0f * tanhf(t3);
    const float a02 = tanhf(t4);
    const float a12 = tanhf(t5);

    __syncthreads();

    float* __restrict__ outF = out + (size_t)n * TH * TW;
    float* __restrict__ outS = out + (size_t)N_IMG * TH * TW + (size_t)n * TH * TW;

    const int lane = tid & 31;   // x position within a 32-wide column group
    const int rsub = tid >> 5;   // 8 row sub-blocks per iteration

    // isx = a00*(px+0.5) + Cx(row), source coords with PAD folded in.
    for (int it = 0; it < 16; ++it) {
        const int py = it * 8 + rsub;
        const float Y  = ((float)py + 0.5f) * (2.0f / TH) - 1.0f;
        const float Cx = 64.0f * (a01 * Y + a02 - a00) + 31.5f;
        const float Cy = 64.0f * (a11 * Y + a12 - a10) + 31.5f;
        float* __restrict__ oF = outF + py * TW + lane;
        float* __restrict__ oS = outS + py * TW + lane;

        #pragma unroll
        for (int j = 0; j < 4; ++j) {
            const float fx  = (float)(lane + 32 * j) + 0.5f;
            const float isx = fmaf(a00, fx, Cx);
            const float isy = fmaf(a10, fx, Cy);

            const float x0f = floorf(isx);
            const float y0f = floorf(isy);
            const float wx  = isx - x0f;
            const float wy  = isy - y0f;

            // clamp into the zero-ringed LDS image; invalid corners read 0
            const int xc = min(max((int)x0f, -2), 64);
            const int yc = min(max((int)y0f, -2), 64);
            const int idx = (yc + 2) * LW + (xc + 2);

            v2f v00 = { sF[idx],          sS[idx]          };
            v2f v10 = { sF[idx + 1],      sS[idx + 1]      };
            v2f v01 = { sF[idx + LW],     sS[idx + LW]     };
            v2f v11 = { sF[idx + LW + 1], sS[idx + LW + 1] };

            const float wxa = 1.0f - wx;
            const float wya = 1.0f - wy;
            v2f r = (wxa * wya) * v00 + (wx * wya) * v10
                  + (wxa * wy ) * v01 + (wx * wy ) * v11;

            oF[32 * j] = r.x;   // coalesced dword stores (lanes stride 1)
            oS[32 * j] = r.y;
        }
    }
}

extern "C" void kernel_launch(void* const* d_in, const int* in_sizes, int n_in,
                              void* d_out, int out_size, void* d_ws, size_t ws_size,
                              hipStream_t stream) {
    const float* affine = (const float*)d_in[0];  // (N, 6)
    const float* fill   = (const float*)d_in[1];  // (N, 64, 64)
    const float* stroke = (const float*)d_in[2];  // (N, 64, 64)
    // d_in[3] = targetsize, unused by the computation.
    float* out = (float*)d_out;                   // fill_out then stroke_out, each (N,128,128)

    affine_sample_kernel<<<dim3(N_IMG), dim3(256), 0, stream>>>(affine, fill, stroke, out);
}